// Round 13
// baseline (1812.210 us; speedup 1.0000x reference)
//
#include <hip/hip_runtime.h>
#include <hip/hip_bf16.h>

#define HH_ 80
#define WW_ 80
#define CIN_ 256
#define NF_ 128
#define NPIX_ 6400   // 80*80

// Module-scope device buffers (26.2 MB; each fully rewritten before read
// every call -> re-poison-safe, graph-safe).
__device__ float g_theta[2 * NPIX_ * NF_];
__device__ float g_phi  [2 * NPIX_ * NF_];
__device__ float g_gv   [2 * NPIX_ * NF_];
__device__ float g_ao   [2 * NPIX_ * NF_];

// ---------------------------------------------------------------------------
// Kernel 1: fused theta/phi/g 3x3 convs (SAME, no bias), fp32 in -> fp32 out
// grid: 2*40*20 = 1600 blocks, 2x4 output-pixel tile, 128 threads (1/filter)
// ---------------------------------------------------------------------------
__global__ __launch_bounds__(128) void conv3_fused(
    const float* __restrict__ x,
    const float* __restrict__ wt,
    const float* __restrict__ wp,
    const float* __restrict__ wg)
{
    __shared__ __align__(16) float patch[24 * 256];   // 4x6 pixels x 256 ch, 24 KB
    const int tid = threadIdx.x;
    const int bid = blockIdx.x;
    const int b  = bid / 800;
    const int t2 = bid % 800;
    const int ty = (t2 / 20) * 2;
    const int tx = (t2 % 20) * 4;
    const float* xb = x + (size_t)b * NPIX_ * CIN_;

    for (int idx = tid; idx < 24 * 64; idx += 128) {
        const int q  = idx & 63;
        const int px = idx >> 6;
        const int pr = px / 6, pc = px % 6;
        const int hh = ty + pr - 1, ww = tx + pc - 1;
        float4 v = make_float4(0.f, 0.f, 0.f, 0.f);
        if (hh >= 0 && hh < HH_ && ww >= 0 && ww < WW_)
            v = *(const float4*)(xb + (size_t)(hh * WW_ + ww) * CIN_ + q * 4);
        *(float4*)(patch + px * 256 + q * 4) = v;
    }
    __syncthreads();

    const int f = tid;
    float at[8], ap[8], ag[8];
    #pragma unroll
    for (int q = 0; q < 8; ++q) { at[q] = 0.f; ap[q] = 0.f; ag[q] = 0.f; }

    for (int k = 0; k < 9; ++k) {
        const int kr = k / 3, kc = k % 3;
        const float* pbase = patch + (kr * 6 + kc) * 256;
        const float* wtp = wt + (size_t)k * CIN_ * NF_ + f;
        const float* wpp = wp + (size_t)k * CIN_ * NF_ + f;
        const float* wgp = wg + (size_t)k * CIN_ * NF_ + f;
        for (int ci = 0; ci < 256; ++ci) {
            const float wtv = wtp[ci * NF_];
            const float wpv = wpp[ci * NF_];
            const float wgv = wgp[ci * NF_];
            #pragma unroll
            for (int i = 0; i < 2; ++i) {
                #pragma unroll
                for (int j = 0; j < 4; ++j) {
                    const float xv = pbase[(i * 6 + j) * 256 + ci];
                    const int q = i * 4 + j;
                    at[q] = fmaf(xv, wtv, at[q]);
                    ap[q] = fmaf(xv, wpv, ap[q]);
                    ag[q] = fmaf(xv, wgv, ag[q]);
                }
            }
        }
    }
    #pragma unroll
    for (int q = 0; q < 8; ++q) {
        const int i = q >> 2, j = q & 3;
        const size_t n = (size_t)b * NPIX_ + (size_t)(ty + i) * WW_ + (tx + j);
        g_theta[n * NF_ + f] = at[q];
        g_phi[n * NF_ + f]   = ap[q];
        g_gv[n * NF_ + f]    = ag[q];
    }
}

// ---------------------------------------------------------------------------
// Kernel 2: flash-style attention, all fp32. Scrambled-phi semantics per the
// reference's row-major reshape NOTE:
//   S[n][m] = sum_c theta[n][c] * phiflat[c*6400 + m],
//   where phiflat is the row-major flattening of phi_conv[n][c].
//   P = softmax_m(S);  ao[n][c] = sum_m P[n][m] * g[m][c]
// grid: 800 blocks x 16 rows; 256 threads; each wave privately owns 4 rows.
// ---------------------------------------------------------------------------
__global__ __launch_bounds__(256) void attn_fused()
{
    __shared__ float4 th_t4[128 * 4];   // [c][rquad], theta tile transposed, 8 KB
    __shared__ float4 s_t4[256 * 5];    // [m][rquad] stride 5 (de-banked), 20 KB
    const int tid = threadIdx.x;
    const int bid = blockIdx.x;          // 0..799
    const int R0 = bid * 16;
    const int b  = R0 / NPIX_;
    const float* phi_b = g_phi + (size_t)b * NPIX_ * NF_;
    const float* g_b   = g_gv  + (size_t)b * NPIX_ * NF_;
    const float* th_g  = g_theta + (size_t)R0 * NF_;

    {   // load 16x128 theta tile transposed into [c][r]
        float* th_s = (float*)th_t4;
        const int r = tid & 15, c0 = tid >> 4;
        #pragma unroll
        for (int it = 0; it < 8; ++it) {
            const int c = c0 + 16 * it;
            th_s[c * 16 + r] = th_g[r * NF_ + c];
        }
    }
    __syncthreads();

    const int rg = tid >> 6;     // wave id: owns rows rg*4 .. rg*4+3
    const int lane = tid & 63;
    float acc0[4], acc1[4], mi[4], li[4];
    #pragma unroll
    for (int i = 0; i < 4; ++i) { acc0[i] = 0.f; acc1[i] = 0.f; mi[i] = -1e30f; li[i] = 0.f; }

    for (int mc = 0; mc < NPIX_; mc += 256) {
        // ---- Phase S: 4 rows x 4 m's per lane -------------------------------
        float sv[4][4];
        #pragma unroll
        for (int i = 0; i < 4; ++i)
            #pragma unroll
            for (int k = 0; k < 4; ++k) sv[i][k] = 0.f;

        const float* pp = phi_b + mc + lane * 4;   // flat [c*6400 + m]
        #pragma unroll 4
        for (int c = 0; c < 128; ++c) {
            const float4 pv = *(const float4*)(pp + (size_t)c * NPIX_);
            const float4 tv = th_t4[c * 4 + rg];
            sv[0][0] = fmaf(tv.x, pv.x, sv[0][0]);
            sv[0][1] = fmaf(tv.x, pv.y, sv[0][1]);
            sv[0][2] = fmaf(tv.x, pv.z, sv[0][2]);
            sv[0][3] = fmaf(tv.x, pv.w, sv[0][3]);
            sv[1][0] = fmaf(tv.y, pv.x, sv[1][0]);
            sv[1][1] = fmaf(tv.y, pv.y, sv[1][1]);
            sv[1][2] = fmaf(tv.y, pv.z, sv[1][2]);
            sv[1][3] = fmaf(tv.y, pv.w, sv[1][3]);
            sv[2][0] = fmaf(tv.z, pv.x, sv[2][0]);
            sv[2][1] = fmaf(tv.z, pv.y, sv[2][1]);
            sv[2][2] = fmaf(tv.z, pv.z, sv[2][2]);
            sv[2][3] = fmaf(tv.z, pv.w, sv[2][3]);
            sv[3][0] = fmaf(tv.w, pv.x, sv[3][0]);
            sv[3][1] = fmaf(tv.w, pv.y, sv[3][1]);
            sv[3][2] = fmaf(tv.w, pv.z, sv[3][2]);
            sv[3][3] = fmaf(tv.w, pv.w, sv[3][3]);
        }

        // ---- online softmax (per-wave rows, register/shuffle only) ----------
        #pragma unroll
        for (int i = 0; i < 4; ++i) {
            float cm = fmaxf(fmaxf(sv[i][0], sv[i][1]), fmaxf(sv[i][2], sv[i][3]));
            #pragma unroll
            for (int off = 32; off > 0; off >>= 1)
                cm = fmaxf(cm, __shfl_xor(cm, off));
            const float nm = fmaxf(mi[i], cm);
            const float al = __expf(mi[i] - nm);
            mi[i] = nm;
            float s0 = 0.f;
            #pragma unroll
            for (int k = 0; k < 4; ++k) { sv[i][k] = __expf(sv[i][k] - nm); s0 += sv[i][k]; }
            #pragma unroll
            for (int off = 32; off > 0; off >>= 1) s0 += __shfl_xor(s0, off);
            li[i] = li[i] * al + s0;
            acc0[i] *= al; acc1[i] *= al;
        }

        // ---- transpose P to [m][rquad] via LDS ------------------------------
        #pragma unroll
        for (int k = 0; k < 4; ++k)
            s_t4[(lane * 4 + k) * 5 + rg] = make_float4(sv[0][k], sv[1][k], sv[2][k], sv[3][k]);
        __syncthreads();

        // ---- Phase PV: acc[r][c] += P[r][m] * g[m][c], lane owns 2 channels -
        const float* gp = g_b + (size_t)mc * NF_ + lane * 2;
        #pragma unroll 4
        for (int m = 0; m < 256; ++m) {
            const float4 p4 = s_t4[m * 5 + rg];              // broadcast read
            const float2 gv = *(const float2*)(gp + (size_t)m * NF_);
            acc0[0] = fmaf(p4.x, gv.x, acc0[0]); acc1[0] = fmaf(p4.x, gv.y, acc1[0]);
            acc0[1] = fmaf(p4.y, gv.x, acc0[1]); acc1[1] = fmaf(p4.y, gv.y, acc1[1]);
            acc0[2] = fmaf(p4.z, gv.x, acc0[2]); acc1[2] = fmaf(p4.z, gv.y, acc1[2]);
            acc0[3] = fmaf(p4.w, gv.x, acc0[3]); acc1[3] = fmaf(p4.w, gv.y, acc1[3]);
        }
        __syncthreads();
    }

    #pragma unroll
    for (int i = 0; i < 4; ++i) {
        const float inv = 1.f / li[i];
        const float2 o = make_float2(acc0[i] * inv, acc1[i] * inv);
        *(float2*)(g_ao + (size_t)(R0 + rg * 4 + i) * NF_ + lane * 2) = o;
    }
}

// ---------------------------------------------------------------------------
// Kernel 3: final 3x3 conv (128 -> 256, fp32) + fp32 residual, FP32 store
// (round-13 fix: d_out is float32 per the reference's output dtype — the
//  bf16-store assumption was the 12-round bug)
// ---------------------------------------------------------------------------
__global__ __launch_bounds__(256) void conv_out_res(
    const float* __restrict__ wc,
    const float* __restrict__ x,
    float* __restrict__ out)
{
    __shared__ __align__(16) float patch[24 * 128];   // 12 KB
    const int tid = threadIdx.x;
    const int bid = blockIdx.x;
    const int b  = bid / 800;
    const int t2 = bid % 800;
    const int ty = (t2 / 20) * 2;
    const int tx = (t2 % 20) * 4;
    const float* aob = g_ao + (size_t)b * NPIX_ * NF_;

    for (int idx = tid; idx < 24 * 32; idx += 256) {
        const int q  = idx & 31;
        const int px = idx >> 5;
        const int pr = px / 6, pc = px % 6;
        const int hh = ty + pr - 1, ww = tx + pc - 1;
        float4 v = make_float4(0.f, 0.f, 0.f, 0.f);
        if (hh >= 0 && hh < HH_ && ww >= 0 && ww < WW_)
            v = *(const float4*)(aob + (size_t)(hh * WW_ + ww) * NF_ + q * 4);
        *(float4*)(patch + px * 128 + q * 4) = v;
    }
    __syncthreads();

    const int f = tid;
    float a[8];
    #pragma unroll
    for (int q = 0; q < 8; ++q) a[q] = 0.f;

    for (int k = 0; k < 9; ++k) {
        const int kr = k / 3, kc = k % 3;
        const float* pbase = patch + (kr * 6 + kc) * 128;
        const float* wp_ = wc + (size_t)k * NF_ * CIN_ + f;
        for (int ci = 0; ci < 128; ++ci) {
            const float wv = wp_[ci * CIN_];
            #pragma unroll
            for (int i = 0; i < 2; ++i) {
                #pragma unroll
                for (int j = 0; j < 4; ++j)
                    a[i * 4 + j] = fmaf(pbase[(i * 6 + j) * 128 + ci], wv, a[i * 4 + j]);
            }
        }
    }
    #pragma unroll
    for (int q = 0; q < 8; ++q) {
        const int i = q >> 2, j = q & 3;
        const size_t oidx = ((size_t)(b * HH_ + ty + i) * WW_ + (tx + j)) * CIN_ + f;
        out[oidx] = x[oidx] + a[q];
    }
}

// ---------------------------------------------------------------------------
extern "C" void kernel_launch(void* const* d_in, const int* in_sizes, int n_in,
                              void* d_out, int out_size, void* d_ws, size_t ws_size,
                              hipStream_t stream)
{
    const float* x  = (const float*)d_in[0];
    const float* wt = (const float*)d_in[1];
    const float* wp = (const float*)d_in[2];
    const float* wg = (const float*)d_in[3];
    const float* wc = (const float*)d_in[4];
    float* out = (float*)d_out;   // FP32 output — the reference returns float32

    conv3_fused<<<1600, 128, 0, stream>>>(x, wt, wp, wg);
    attn_fused<<<800, 256, 0, stream>>>();
    conv_out_res<<<1600, 256, 0, stream>>>(wc, x, out);
}

// Round 14
// 1303.282 us; speedup vs baseline: 1.3905x; 1.3905x over previous
//
#include <hip/hip_runtime.h>
#include <hip/hip_bf16.h>

#define HH_ 80
#define WW_ 80
#define CIN_ 256
#define NF_ 128
#define NPIX_ 6400   // 80*80
#define NTOK_ (2 * NPIX_)          // 12800 rows total
#define NELEM_ (NTOK_ * NF_)       // 1,638,400

// fp32 intermediates (conv outputs, attention output)
__device__ float g_theta[NELEM_];
__device__ float g_phi  [NELEM_];
__device__ float g_gv   [NELEM_];
__device__ float g_ao   [NELEM_];
// bf16-packed operands for MFMA attention
__device__ unsigned short g_th_hi[NELEM_];   // theta hi  [n][c]
__device__ unsigned short g_th_lo[NELEM_];   // theta lo  [n][c]
__device__ unsigned short g_phT_hi[NELEM_];  // phi^T hi  [b][m][c]  (scrambled view)
__device__ unsigned short g_phT_lo[NELEM_];  // phi^T lo  [b][m][c]
__device__ unsigned short g_gT   [NELEM_];   // g^T       [b][ch][m]

__device__ __forceinline__ float b2f(unsigned short u) {
    union { unsigned int i; float f; } v; v.i = ((unsigned int)u) << 16; return v.f;
}
__device__ __forceinline__ unsigned short f2b(float f) {
    union { float f; unsigned int i; } v; v.f = f;
    unsigned int i = v.i;
    i += 0x7fffu + ((i >> 16) & 1u);   // RNE (finite only)
    return (unsigned short)(i >> 16);
}

typedef __attribute__((ext_vector_type(8))) short bf16x8;
typedef __attribute__((ext_vector_type(4))) float f32x4;

__device__ __forceinline__ f32x4 mfma16(bf16x8 a, bf16x8 b, f32x4 c) {
    return __builtin_amdgcn_mfma_f32_16x16x32_bf16(a, b, c, 0, 0, 0);
}

// ---------------------------------------------------------------------------
// Kernel 1: fused theta/phi/g 3x3 convs (SAME, no bias), fp32 in -> fp32 out
// ---------------------------------------------------------------------------
__global__ __launch_bounds__(128) void conv3_fused(
    const float* __restrict__ x,
    const float* __restrict__ wt,
    const float* __restrict__ wp,
    const float* __restrict__ wg)
{
    __shared__ __align__(16) float patch[24 * 256];
    const int tid = threadIdx.x;
    const int bid = blockIdx.x;
    const int b  = bid / 800;
    const int t2 = bid % 800;
    const int ty = (t2 / 20) * 2;
    const int tx = (t2 % 20) * 4;
    const float* xb = x + (size_t)b * NPIX_ * CIN_;

    for (int idx = tid; idx < 24 * 64; idx += 128) {
        const int q  = idx & 63;
        const int px = idx >> 6;
        const int pr = px / 6, pc = px % 6;
        const int hh = ty + pr - 1, ww = tx + pc - 1;
        float4 v = make_float4(0.f, 0.f, 0.f, 0.f);
        if (hh >= 0 && hh < HH_ && ww >= 0 && ww < WW_)
            v = *(const float4*)(xb + (size_t)(hh * WW_ + ww) * CIN_ + q * 4);
        *(float4*)(patch + px * 256 + q * 4) = v;
    }
    __syncthreads();

    const int f = tid;
    float at[8], ap[8], ag[8];
    #pragma unroll
    for (int q = 0; q < 8; ++q) { at[q] = 0.f; ap[q] = 0.f; ag[q] = 0.f; }

    for (int k = 0; k < 9; ++k) {
        const int kr = k / 3, kc = k % 3;
        const float* pbase = patch + (kr * 6 + kc) * 256;
        const float* wtp = wt + (size_t)k * CIN_ * NF_ + f;
        const float* wpp = wp + (size_t)k * CIN_ * NF_ + f;
        const float* wgp = wg + (size_t)k * CIN_ * NF_ + f;
        for (int ci = 0; ci < 256; ++ci) {
            const float wtv = wtp[ci * NF_];
            const float wpv = wpp[ci * NF_];
            const float wgv = wgp[ci * NF_];
            #pragma unroll
            for (int i = 0; i < 2; ++i) {
                #pragma unroll
                for (int j = 0; j < 4; ++j) {
                    const float xv = pbase[(i * 6 + j) * 256 + ci];
                    const int q = i * 4 + j;
                    at[q] = fmaf(xv, wtv, at[q]);
                    ap[q] = fmaf(xv, wpv, ap[q]);
                    ag[q] = fmaf(xv, wgv, ag[q]);
                }
            }
        }
    }
    #pragma unroll
    for (int q = 0; q < 8; ++q) {
        const int i = q >> 2, j = q & 3;
        const size_t n = (size_t)b * NPIX_ + (size_t)(ty + i) * WW_ + (tx + j);
        g_theta[n * NF_ + f] = at[q];
        g_phi[n * NF_ + f]   = ap[q];
        g_gv[n * NF_ + f]    = ag[q];
    }
}

// ---------------------------------------------------------------------------
// Kernel 1b: pack/transpose fp32 conv outputs to bf16 MFMA operand layouts.
//   th_hi/lo[n][c];  phT_hi/lo[b][m][c] with Phi[c][m]=phi_flat_b[c*6400+m];
//   gT[b][ch][m].
// ---------------------------------------------------------------------------
__global__ __launch_bounds__(256) void prep_pack()
{
    const int i = blockIdx.x * 256 + threadIdx.x;
    if (i >= NELEM_) return;
    const int n  = i >> 7;        // 0..12799
    const int c  = i & 127;
    const int b  = n / NPIX_;
    const int nl = n % NPIX_;

    const float tv = g_theta[i];
    const unsigned short th = f2b(tv);
    g_th_hi[i] = th;
    g_th_lo[i] = f2b(tv - b2f(th));

    const float pv = g_phi[i];
    const int j  = nl * 128 + c;          // flat index within batch
    const int cp = j / NPIX_;             // scrambled-view channel
    const int mp = j % NPIX_;             // scrambled-view position
    const unsigned short ph = f2b(pv);
    const size_t o = (size_t)b * (NPIX_ * NF_) + (size_t)mp * 128 + cp;
    g_phT_hi[o] = ph;
    g_phT_lo[o] = f2b(pv - b2f(ph));

    g_gT[(size_t)b * (NPIX_ * NF_) + (size_t)c * NPIX_ + nl] = f2b(g_gv[i]);
}

// ---------------------------------------------------------------------------
// Kernel 2: MFMA flash attention.
//   S[n][m] = th[n][:]·phT[m][:]  (hi/lo split: 3 MFMAs per k-step, ~fp32)
//   P = online-softmax_m(S);  ao[n][ch] = P·g  (bf16 P & g, fp32 acc)
// 800 blocks x 16 Q-rows; 4 waves split m-space (split-KV), merge at end.
// Layouts (HW-verified): A[m=lane&15][k=quad*8+j]; C/D row=quad*4+reg,
// col=lane&15 -> S-acc and O-acc share the row mapping (alpha rescale is
// a per-reg multiply).
// ---------------------------------------------------------------------------
__global__ __launch_bounds__(256) void attn_mfma()
{
    __shared__ __align__(16) short p_lds[4][16 * 72];  // P tile [n][m], pad 72
    __shared__ float o_lds[4][16][132];                // per-wave O partials
    __shared__ float ml_lds[4][16][2];                 // per-wave (m_i, l_i)

    const int tid  = threadIdx.x;
    const int w    = tid >> 6;
    const int lane = tid & 63;
    const int quad = lane >> 4;
    const int ll   = lane & 15;
    const int R0   = blockIdx.x * 16;     // 16 Q-rows (never straddles batch)
    const int b    = R0 / NPIX_;

    const unsigned short* phH = g_phT_hi + (size_t)b * (NPIX_ * NF_);
    const unsigned short* phL = g_phT_lo + (size_t)b * (NPIX_ * NF_);
    const unsigned short* gT  = g_gT    + (size_t)b * (NPIX_ * NF_);

    // theta A-fragments, 4 k-steps x {hi,lo} — loaded once
    bf16x8 aH[4], aL[4];
    #pragma unroll
    for (int kk = 0; kk < 4; ++kk) {
        const size_t off = (size_t)(R0 + ll) * 128 + kk * 32 + quad * 8;
        aH[kk] = *(const bf16x8*)(g_th_hi + off);
        aL[kk] = *(const bf16x8*)(g_th_lo + off);
    }

    f32x4 acc[8];
    #pragma unroll
    for (int t = 0; t < 8; ++t) acc[t] = (f32x4){0.f, 0.f, 0.f, 0.f};
    float mi[4] = {-1e30f, -1e30f, -1e30f, -1e30f};
    float li[4] = {0.f, 0.f, 0.f, 0.f};

    short* pl = &p_lds[w][0];

    for (int it = 0; it < 25; ++it) {
        const int m0 = it * 256 + w * 64;   // this wave's 64-m chunk

        // ---- S phase: 4 m-tiles of 16, K=128 in 4 steps, hi/lo split ------
        f32x4 s[4];
        #pragma unroll
        for (int mt = 0; mt < 4; ++mt) {
            f32x4 a_s = (f32x4){0.f, 0.f, 0.f, 0.f};
            const int mm = m0 + mt * 16 + ll;
            #pragma unroll
            for (int kk = 0; kk < 4; ++kk) {
                const size_t off = (size_t)mm * 128 + kk * 32 + quad * 8;
                const bf16x8 bH = *(const bf16x8*)(phH + off);
                const bf16x8 bL = *(const bf16x8*)(phL + off);
                a_s = mfma16(aH[kk], bH, a_s);
                a_s = mfma16(aH[kk], bL, a_s);
                a_s = mfma16(aL[kk], bH, a_s);
            }
            s[mt] = a_s;
        }

        // ---- online softmax: row r lives on the 16 lanes of this quad -----
        #pragma unroll
        for (int r = 0; r < 4; ++r) {
            float cm = fmaxf(fmaxf(s[0][r], s[1][r]), fmaxf(s[2][r], s[3][r]));
            cm = fmaxf(cm, __shfl_xor(cm, 1));
            cm = fmaxf(cm, __shfl_xor(cm, 2));
            cm = fmaxf(cm, __shfl_xor(cm, 4));
            cm = fmaxf(cm, __shfl_xor(cm, 8));
            const float nm = fmaxf(mi[r], cm);
            const float al = __expf(mi[r] - nm);
            mi[r] = nm;
            float s0 = 0.f;
            #pragma unroll
            for (int mt = 0; mt < 4; ++mt) {
                const float e = __expf(s[mt][r] - nm);
                s[mt][r] = e; s0 += e;
            }
            s0 += __shfl_xor(s0, 1);
            s0 += __shfl_xor(s0, 2);
            s0 += __shfl_xor(s0, 4);
            s0 += __shfl_xor(s0, 8);
            li[r] = li[r] * al + s0;
            #pragma unroll
            for (int t = 0; t < 8; ++t) acc[t][r] *= al;
        }

        // ---- P (C-layout) -> LDS [n][m] bf16 -> A-fragments ---------------
        #pragma unroll
        for (int mt = 0; mt < 4; ++mt)
            #pragma unroll
            for (int r = 0; r < 4; ++r)
                pl[(quad * 4 + r) * 72 + mt * 16 + ll] = (short)f2b(s[mt][r]);
        bf16x8 pa[2];
        #pragma unroll
        for (int ks = 0; ks < 2; ++ks)
            pa[ks] = *(const bf16x8*)(pl + ll * 72 + ks * 32 + quad * 8);

        // ---- PV: 8 channel-tiles x 2 k-steps ------------------------------
        #pragma unroll
        for (int ct = 0; ct < 8; ++ct) {
            #pragma unroll
            for (int ks = 0; ks < 2; ++ks) {
                const bf16x8 gb = *(const bf16x8*)(
                    gT + (size_t)(ct * 16 + ll) * NPIX_ + m0 + ks * 32 + quad * 8);
                acc[ct] = mfma16(pa[ks], gb, acc[ct]);
            }
        }
    }

    // ---- split-KV merge across the 4 waves --------------------------------
    #pragma unroll
    for (int ct = 0; ct < 8; ++ct)
        #pragma unroll
        for (int r = 0; r < 4; ++r)
            o_lds[w][quad * 4 + r][ct * 16 + ll] = acc[ct][r];
    if (ll == 0) {
        #pragma unroll
        for (int r = 0; r < 4; ++r) {
            ml_lds[w][quad * 4 + r][0] = mi[r];
            ml_lds[w][quad * 4 + r][1] = li[r];
        }
    }
    __syncthreads();

    const int n  = tid >> 4;
    const int c0 = (tid & 15) * 8;
    const float M = fmaxf(fmaxf(ml_lds[0][n][0], ml_lds[1][n][0]),
                          fmaxf(ml_lds[2][n][0], ml_lds[3][n][0]));
    float sc[4], L = 0.f;
    #pragma unroll
    for (int ww = 0; ww < 4; ++ww) {
        sc[ww] = __expf(ml_lds[ww][n][0] - M);
        L += ml_lds[ww][n][1] * sc[ww];
    }
    const float inv = 1.f / L;
    #pragma unroll
    for (int j = 0; j < 8; ++j) {
        float o = 0.f;
        #pragma unroll
        for (int ww = 0; ww < 4; ++ww) o += o_lds[ww][n][c0 + j] * sc[ww];
        g_ao[(size_t)(R0 + n) * 128 + c0 + j] = o * inv;
    }
}

// ---------------------------------------------------------------------------
// Kernel 3: final 3x3 conv (128 -> 256, fp32) + fp32 residual, fp32 store
// ---------------------------------------------------------------------------
__global__ __launch_bounds__(256) void conv_out_res(
    const float* __restrict__ wc,
    const float* __restrict__ x,
    float* __restrict__ out)
{
    __shared__ __align__(16) float patch[24 * 128];
    const int tid = threadIdx.x;
    const int bid = blockIdx.x;
    const int b  = bid / 800;
    const int t2 = bid % 800;
    const int ty = (t2 / 20) * 2;
    const int tx = (t2 % 20) * 4;
    const float* aob = g_ao + (size_t)b * NPIX_ * NF_;

    for (int idx = tid; idx < 24 * 32; idx += 256) {
        const int q  = idx & 31;
        const int px = idx >> 5;
        const int pr = px / 6, pc = px % 6;
        const int hh = ty + pr - 1, ww = tx + pc - 1;
        float4 v = make_float4(0.f, 0.f, 0.f, 0.f);
        if (hh >= 0 && hh < HH_ && ww >= 0 && ww < WW_)
            v = *(const float4*)(aob + (size_t)(hh * WW_ + ww) * NF_ + q * 4);
        *(float4*)(patch + px * 128 + q * 4) = v;
    }
    __syncthreads();

    const int f = tid;
    float a[8];
    #pragma unroll
    for (int q = 0; q < 8; ++q) a[q] = 0.f;

    for (int k = 0; k < 9; ++k) {
        const int kr = k / 3, kc = k % 3;
        const float* pbase = patch + (kr * 6 + kc) * 128;
        const float* wp_ = wc + (size_t)k * NF_ * CIN_ + f;
        for (int ci = 0; ci < 128; ++ci) {
            const float wv = wp_[ci * CIN_];
            #pragma unroll
            for (int i = 0; i < 2; ++i) {
                #pragma unroll
                for (int j = 0; j < 4; ++j)
                    a[i * 4 + j] = fmaf(pbase[(i * 6 + j) * 128 + ci], wv, a[i * 4 + j]);
            }
        }
    }
    #pragma unroll
    for (int q = 0; q < 8; ++q) {
        const int i = q >> 2, j = q & 3;
        const size_t oidx = ((size_t)(b * HH_ + ty + i) * WW_ + (tx + j)) * CIN_ + f;
        out[oidx] = x[oidx] + a[q];
    }
}

// ---------------------------------------------------------------------------
extern "C" void kernel_launch(void* const* d_in, const int* in_sizes, int n_in,
                              void* d_out, int out_size, void* d_ws, size_t ws_size,
                              hipStream_t stream)
{
    const float* x  = (const float*)d_in[0];
    const float* wt = (const float*)d_in[1];
    const float* wp = (const float*)d_in[2];
    const float* wg = (const float*)d_in[3];
    const float* wc = (const float*)d_in[4];
    float* out = (float*)d_out;

    conv3_fused<<<1600, 128, 0, stream>>>(x, wt, wp, wg);
    prep_pack<<<(NELEM_ + 255) / 256, 256, 0, stream>>>();
    attn_mfma<<<800, 256, 0, stream>>>();
    conv_out_res<<<1600, 256, 0, stream>>>(wc, x, out);
}

// Round 15
// 946.007 us; speedup vs baseline: 1.9156x; 1.3777x over previous
//
#include <hip/hip_runtime.h>
#include <hip/hip_bf16.h>

#define HH_ 80
#define WW_ 80
#define CIN_ 256
#define NF_ 128
#define NPIX_ 6400
#define NTOK_ 12800
#define NELEM_ (NTOK_ * NF_)       // 1,638,400
#define NXEL_  (NTOK_ * CIN_)      // 3,276,800
#define KW_    2304                // 9*256  (conv3 K)
#define KWC_   1152                // 9*128  (conv_out K)
#define WEL_   294912              // 9*256*128 == 9*128*256

// fp32 conv outputs (consumed by prep_pack)
__device__ float g_theta[NELEM_];
__device__ float g_phi  [NELEM_];
__device__ float g_gv   [NELEM_];
// bf16 attention output (consumed by conv_out_mfma)
__device__ unsigned short g_aob[NELEM_];
// bf16 MFMA operands for attention
__device__ unsigned short g_th_hi[NELEM_], g_th_lo[NELEM_];
__device__ unsigned short g_phT_hi[NELEM_], g_phT_lo[NELEM_];
__device__ unsigned short g_gT[NELEM_];
// bf16 hi/lo split of x, and transposed bf16 weights [f][k]
__device__ unsigned short g_xh[NXEL_], g_xl[NXEL_];
__device__ unsigned short g_wtTh[WEL_], g_wtTl[WEL_];
__device__ unsigned short g_wpTh[WEL_], g_wpTl[WEL_];
__device__ unsigned short g_wgT[WEL_];
__device__ unsigned short g_wcT[WEL_];

__device__ __forceinline__ float b2f(unsigned short u) {
    union { unsigned int i; float f; } v; v.i = ((unsigned int)u) << 16; return v.f;
}
__device__ __forceinline__ unsigned short f2b(float f) {
    union { float f; unsigned int i; } v; v.f = f;
    unsigned int i = v.i;
    i += 0x7fffu + ((i >> 16) & 1u);   // RNE (finite only)
    return (unsigned short)(i >> 16);
}

typedef __attribute__((ext_vector_type(8))) short bf16x8;
typedef __attribute__((ext_vector_type(4))) float f32x4;

__device__ __forceinline__ f32x4 mfma16(bf16x8 a, bf16x8 b, f32x4 c) {
    return __builtin_amdgcn_mfma_f32_16x16x32_bf16(a, b, c, 0, 0, 0);
}

// ---------------------------------------------------------------------------
// prep_x: fp32 x -> bf16 hi/lo split
// ---------------------------------------------------------------------------
__global__ __launch_bounds__(256) void prep_x(const float* __restrict__ x)
{
    const int i = (blockIdx.x * 256 + threadIdx.x) * 4;
    if (i >= NXEL_) return;
    const float4 v = *(const float4*)(x + i);
    ushort4 hi, lo;
    hi.x = f2b(v.x); lo.x = f2b(v.x - b2f(hi.x));
    hi.y = f2b(v.y); lo.y = f2b(v.y - b2f(hi.y));
    hi.z = f2b(v.z); lo.z = f2b(v.z - b2f(hi.z));
    hi.w = f2b(v.w); lo.w = f2b(v.w - b2f(hi.w));
    *(ushort4*)(g_xh + i) = hi;
    *(ushort4*)(g_xl + i) = lo;
}

// ---------------------------------------------------------------------------
// prep_w: transpose HWIO weights to [f][k] bf16 (hi/lo for w_theta/w_phi)
// ---------------------------------------------------------------------------
__global__ __launch_bounds__(256) void prep_w(
    const float* __restrict__ wt, const float* __restrict__ wp,
    const float* __restrict__ wg, const float* __restrict__ wc)
{
    const int i = blockIdx.x * 256 + threadIdx.x;
    if (i >= WEL_) return;
    // 256-in/128-out convs: i = (t*256+ci)*128 + f
    {
        const int t  = i / (256 * 128);
        const int r  = i % (256 * 128);
        const int ci = r >> 7;
        const int f  = r & 127;
        const size_t d = (size_t)f * KW_ + t * 256 + ci;
        const float tv = wt[i];
        const unsigned short th = f2b(tv);
        g_wtTh[d] = th; g_wtTl[d] = f2b(tv - b2f(th));
        const float pv = wp[i];
        const unsigned short ph = f2b(pv);
        g_wpTh[d] = ph; g_wpTl[d] = f2b(pv - b2f(ph));
        g_wgT[d] = f2b(wg[i]);
    }
    // 128-in/256-out conv: i = (t*128+ci)*256 + f
    {
        const int t  = i / (128 * 256);
        const int r  = i % (128 * 256);
        const int ci = r >> 8;
        const int f  = r & 255;
        g_wcT[(size_t)f * KWC_ + t * 128 + ci] = f2b(wc[i]);
    }
}

// ---------------------------------------------------------------------------
// conv3_mfma: implicit-GEMM 3x3 conv, 3 heads fused.
//   D[p][f] = sum_{t,ci} X[p+off(t)][ci] * W[f][t*256+ci]
// theta/phi: hi/lo 3-term (~fp32); g: single bf16.
// 400 blocks x 256 thr; block = 32 pixels; wave w = filters w*32..+31.
// Fragment roles (HW-verified r14): A lane ll = row (pixel), B lane ll = col
// (filter), k contiguous 8 at quad*8; D row=quad*4+reg, col=ll.
// ---------------------------------------------------------------------------
__global__ __launch_bounds__(256) void conv3_mfma()
{
    const int tid = threadIdx.x;
    const int w = tid >> 6, lane = tid & 63, quad = lane >> 4, ll = lane & 15;
    const int P0 = blockIdx.x * 32;
    const int fb = w * 32;

    int pb[2], ph[2], pw[2];
    #pragma unroll
    for (int pt = 0; pt < 2; ++pt) {
        const int p = P0 + pt * 16 + ll;
        pb[pt] = p / NPIX_;
        const int pl_ = p % NPIX_;
        ph[pt] = pl_ / WW_;
        pw[pt] = pl_ % WW_;
    }

    const bf16x8 ZV = {0,0,0,0,0,0,0,0};
    f32x4 aT[2][2], aP[2][2], aG[2][2];
    #pragma unroll
    for (int pt = 0; pt < 2; ++pt)
        #pragma unroll
        for (int ft = 0; ft < 2; ++ft) {
            aT[pt][ft] = (f32x4){0.f,0.f,0.f,0.f};
            aP[pt][ft] = (f32x4){0.f,0.f,0.f,0.f};
            aG[pt][ft] = (f32x4){0.f,0.f,0.f,0.f};
        }

    for (int t = 0; t < 9; ++t) {
        const int dh = t / 3 - 1, dw = t % 3 - 1;
        size_t abase[2]; bool av[2];
        #pragma unroll
        for (int pt = 0; pt < 2; ++pt) {
            const int hh = ph[pt] + dh, ww2 = pw[pt] + dw;
            av[pt] = (hh >= 0 && hh < HH_ && ww2 >= 0 && ww2 < WW_);
            abase[pt] = ((size_t)pb[pt] * NPIX_ + hh * WW_ + ww2) * CIN_;
        }
        const int wkb = t * 256;
        for (int kc = 0; kc < 8; ++kc) {
            const int ko = kc * 32 + quad * 8;
            bf16x8 aH[2], aL[2];
            #pragma unroll
            for (int pt = 0; pt < 2; ++pt) {
                if (av[pt]) {
                    aH[pt] = *(const bf16x8*)(g_xh + abase[pt] + ko);
                    aL[pt] = *(const bf16x8*)(g_xl + abase[pt] + ko);
                } else { aH[pt] = ZV; aL[pt] = ZV; }
            }
            const int wk = wkb + ko;
            #pragma unroll
            for (int ft = 0; ft < 2; ++ft) {
                const size_t wo = (size_t)(fb + ft * 16 + ll) * KW_ + wk;
                const bf16x8 tH = *(const bf16x8*)(g_wtTh + wo);
                const bf16x8 tL = *(const bf16x8*)(g_wtTl + wo);
                const bf16x8 pH = *(const bf16x8*)(g_wpTh + wo);
                const bf16x8 pL = *(const bf16x8*)(g_wpTl + wo);
                const bf16x8 gB = *(const bf16x8*)(g_wgT + wo);
                #pragma unroll
                for (int pt = 0; pt < 2; ++pt) {
                    aT[pt][ft] = mfma16(aH[pt], tH, aT[pt][ft]);
                    aT[pt][ft] = mfma16(aH[pt], tL, aT[pt][ft]);
                    aT[pt][ft] = mfma16(aL[pt], tH, aT[pt][ft]);
                    aP[pt][ft] = mfma16(aH[pt], pH, aP[pt][ft]);
                    aP[pt][ft] = mfma16(aH[pt], pL, aP[pt][ft]);
                    aP[pt][ft] = mfma16(aL[pt], pH, aP[pt][ft]);
                    aG[pt][ft] = mfma16(aH[pt], gB, aG[pt][ft]);
                }
            }
        }
    }

    #pragma unroll
    for (int pt = 0; pt < 2; ++pt)
        #pragma unroll
        for (int ft = 0; ft < 2; ++ft) {
            const int f = fb + ft * 16 + ll;
            #pragma unroll
            for (int r = 0; r < 4; ++r) {
                const size_t n = P0 + pt * 16 + quad * 4 + r;
                g_theta[n * NF_ + f] = aT[pt][ft][r];
                g_phi  [n * NF_ + f] = aP[pt][ft][r];
                g_gv   [n * NF_ + f] = aG[pt][ft][r];
            }
        }
}

// ---------------------------------------------------------------------------
// prep_pack: fp32 conv outputs -> bf16 MFMA operand layouts (r14, verified)
// ---------------------------------------------------------------------------
__global__ __launch_bounds__(256) void prep_pack()
{
    const int i = blockIdx.x * 256 + threadIdx.x;
    if (i >= NELEM_) return;
    const int n  = i >> 7;
    const int c  = i & 127;
    const int b  = n / NPIX_;
    const int nl = n % NPIX_;

    const float tv = g_theta[i];
    const unsigned short th = f2b(tv);
    g_th_hi[i] = th;
    g_th_lo[i] = f2b(tv - b2f(th));

    const float pv = g_phi[i];
    const int j  = nl * 128 + c;
    const int cp = j / NPIX_;
    const int mp = j % NPIX_;
    const unsigned short phh = f2b(pv);
    const size_t o = (size_t)b * (NPIX_ * NF_) + (size_t)mp * 128 + cp;
    g_phT_hi[o] = phh;
    g_phT_lo[o] = f2b(pv - b2f(phh));

    g_gT[(size_t)b * (NPIX_ * NF_) + (size_t)c * NPIX_ + nl] = f2b(g_gv[i]);
}

// ---------------------------------------------------------------------------
// attn_mfma (r14, verified): epilogue now writes bf16 g_aob
// ---------------------------------------------------------------------------
__global__ __launch_bounds__(256) void attn_mfma()
{
    __shared__ __align__(16) short p_lds[4][16 * 72];
    __shared__ float o_lds[4][16][132];
    __shared__ float ml_lds[4][16][2];

    const int tid  = threadIdx.x;
    const int w    = tid >> 6;
    const int lane = tid & 63;
    const int quad = lane >> 4;
    const int ll   = lane & 15;
    const int R0   = blockIdx.x * 16;
    const int b    = R0 / NPIX_;

    const unsigned short* phH = g_phT_hi + (size_t)b * (NPIX_ * NF_);
    const unsigned short* phL = g_phT_lo + (size_t)b * (NPIX_ * NF_);
    const unsigned short* gT  = g_gT    + (size_t)b * (NPIX_ * NF_);

    bf16x8 aH[4], aL[4];
    #pragma unroll
    for (int kk = 0; kk < 4; ++kk) {
        const size_t off = (size_t)(R0 + ll) * 128 + kk * 32 + quad * 8;
        aH[kk] = *(const bf16x8*)(g_th_hi + off);
        aL[kk] = *(const bf16x8*)(g_th_lo + off);
    }

    f32x4 acc[8];
    #pragma unroll
    for (int t = 0; t < 8; ++t) acc[t] = (f32x4){0.f, 0.f, 0.f, 0.f};
    float mi[4] = {-1e30f, -1e30f, -1e30f, -1e30f};
    float li[4] = {0.f, 0.f, 0.f, 0.f};

    short* pl = &p_lds[w][0];

    for (int it = 0; it < 25; ++it) {
        const int m0 = it * 256 + w * 64;

        f32x4 s[4];
        #pragma unroll
        for (int mt = 0; mt < 4; ++mt) {
            f32x4 a_s = (f32x4){0.f, 0.f, 0.f, 0.f};
            const int mm = m0 + mt * 16 + ll;
            #pragma unroll
            for (int kk = 0; kk < 4; ++kk) {
                const size_t off = (size_t)mm * 128 + kk * 32 + quad * 8;
                const bf16x8 bH = *(const bf16x8*)(phH + off);
                const bf16x8 bL = *(const bf16x8*)(phL + off);
                a_s = mfma16(aH[kk], bH, a_s);
                a_s = mfma16(aH[kk], bL, a_s);
                a_s = mfma16(aL[kk], bH, a_s);
            }
            s[mt] = a_s;
        }

        #pragma unroll
        for (int r = 0; r < 4; ++r) {
            float cm = fmaxf(fmaxf(s[0][r], s[1][r]), fmaxf(s[2][r], s[3][r]));
            cm = fmaxf(cm, __shfl_xor(cm, 1));
            cm = fmaxf(cm, __shfl_xor(cm, 2));
            cm = fmaxf(cm, __shfl_xor(cm, 4));
            cm = fmaxf(cm, __shfl_xor(cm, 8));
            const float nm = fmaxf(mi[r], cm);
            const float al = __expf(mi[r] - nm);
            mi[r] = nm;
            float s0 = 0.f;
            #pragma unroll
            for (int mt = 0; mt < 4; ++mt) {
                const float e = __expf(s[mt][r] - nm);
                s[mt][r] = e; s0 += e;
            }
            s0 += __shfl_xor(s0, 1);
            s0 += __shfl_xor(s0, 2);
            s0 += __shfl_xor(s0, 4);
            s0 += __shfl_xor(s0, 8);
            li[r] = li[r] * al + s0;
            #pragma unroll
            for (int t = 0; t < 8; ++t) acc[t][r] *= al;
        }

        #pragma unroll
        for (int mt = 0; mt < 4; ++mt)
            #pragma unroll
            for (int r = 0; r < 4; ++r)
                pl[(quad * 4 + r) * 72 + mt * 16 + ll] = (short)f2b(s[mt][r]);
        bf16x8 pa[2];
        #pragma unroll
        for (int ks = 0; ks < 2; ++ks)
            pa[ks] = *(const bf16x8*)(pl + ll * 72 + ks * 32 + quad * 8);

        #pragma unroll
        for (int ct = 0; ct < 8; ++ct) {
            #pragma unroll
            for (int ks = 0; ks < 2; ++ks) {
                const bf16x8 gb = *(const bf16x8*)(
                    gT + (size_t)(ct * 16 + ll) * NPIX_ + m0 + ks * 32 + quad * 8);
                acc[ct] = mfma16(pa[ks], gb, acc[ct]);
            }
        }
    }

    #pragma unroll
    for (int ct = 0; ct < 8; ++ct)
        #pragma unroll
        for (int r = 0; r < 4; ++r)
            o_lds[w][quad * 4 + r][ct * 16 + ll] = acc[ct][r];
    if (ll == 0) {
        #pragma unroll
        for (int r = 0; r < 4; ++r) {
            ml_lds[w][quad * 4 + r][0] = mi[r];
            ml_lds[w][quad * 4 + r][1] = li[r];
        }
    }
    __syncthreads();

    const int n  = tid >> 4;
    const int c0 = (tid & 15) * 8;
    const float M = fmaxf(fmaxf(ml_lds[0][n][0], ml_lds[1][n][0]),
                          fmaxf(ml_lds[2][n][0], ml_lds[3][n][0]));
    float sc[4], L = 0.f;
    #pragma unroll
    for (int ww = 0; ww < 4; ++ww) {
        sc[ww] = __expf(ml_lds[ww][n][0] - M);
        L += ml_lds[ww][n][1] * sc[ww];
    }
    const float inv = 1.f / L;
    ushort4 o4a, o4b;
    unsigned short tmp[8];
    #pragma unroll
    for (int j = 0; j < 8; ++j) {
        float o = 0.f;
        #pragma unroll
        for (int ww = 0; ww < 4; ++ww) o += o_lds[ww][n][c0 + j] * sc[ww];
        tmp[j] = f2b(o * inv);
    }
    o4a = make_ushort4(tmp[0], tmp[1], tmp[2], tmp[3]);
    o4b = make_ushort4(tmp[4], tmp[5], tmp[6], tmp[7]);
    *(ushort4*)(g_aob + (size_t)(R0 + n) * 128 + c0)     = o4a;
    *(ushort4*)(g_aob + (size_t)(R0 + n) * 128 + c0 + 4) = o4b;
}

// ---------------------------------------------------------------------------
// conv_out_mfma: implicit-GEMM 3x3 conv (128->256, bf16) + fp32 residual
// 400 blocks x 256 thr; block = 32 pixels; wave w = filters w*64..+63.
// ---------------------------------------------------------------------------
__global__ __launch_bounds__(256) void conv_out_mfma(
    const float* __restrict__ x, float* __restrict__ out)
{
    const int tid = threadIdx.x;
    const int w = tid >> 6, lane = tid & 63, quad = lane >> 4, ll = lane & 15;
    const int P0 = blockIdx.x * 32;
    const int fb = w * 64;

    int pb[2], ph[2], pw[2];
    #pragma unroll
    for (int pt = 0; pt < 2; ++pt) {
        const int p = P0 + pt * 16 + ll;
        pb[pt] = p / NPIX_;
        const int pl_ = p % NPIX_;
        ph[pt] = pl_ / WW_;
        pw[pt] = pl_ % WW_;
    }

    const bf16x8 ZV = {0,0,0,0,0,0,0,0};
    f32x4 acc[2][4];
    #pragma unroll
    for (int pt = 0; pt < 2; ++pt)
        #pragma unroll
        for (int ft = 0; ft < 4; ++ft) acc[pt][ft] = (f32x4){0.f,0.f,0.f,0.f};

    for (int t = 0; t < 9; ++t) {
        const int dh = t / 3 - 1, dw = t % 3 - 1;
        size_t abase[2]; bool av[2];
        #pragma unroll
        for (int pt = 0; pt < 2; ++pt) {
            const int hh = ph[pt] + dh, ww2 = pw[pt] + dw;
            av[pt] = (hh >= 0 && hh < HH_ && ww2 >= 0 && ww2 < WW_);
            abase[pt] = ((size_t)pb[pt] * NPIX_ + hh * WW_ + ww2) * NF_;
        }
        for (int kc = 0; kc < 4; ++kc) {
            const int ko = kc * 32 + quad * 8;
            bf16x8 a[2];
            #pragma unroll
            for (int pt = 0; pt < 2; ++pt)
                a[pt] = av[pt] ? *(const bf16x8*)(g_aob + abase[pt] + ko) : ZV;
            const int wk = t * 128 + ko;
            #pragma unroll
            for (int ft = 0; ft < 4; ++ft) {
                const bf16x8 bw = *(const bf16x8*)(
                    g_wcT + (size_t)(fb + ft * 16 + ll) * KWC_ + wk);
                #pragma unroll
                for (int pt = 0; pt < 2; ++pt)
                    acc[pt][ft] = mfma16(a[pt], bw, acc[pt][ft]);
            }
        }
    }

    #pragma unroll
    for (int pt = 0; pt < 2; ++pt)
        #pragma unroll
        for (int ft = 0; ft < 4; ++ft) {
            const int f = fb + ft * 16 + ll;
            #pragma unroll
            for (int r = 0; r < 4; ++r) {
                const size_t n = P0 + pt * 16 + quad * 4 + r;
                const size_t oi = n * CIN_ + f;
                out[oi] = x[oi] + acc[pt][ft][r];
            }
        }
}

// ---------------------------------------------------------------------------
extern "C" void kernel_launch(void* const* d_in, const int* in_sizes, int n_in,
                              void* d_out, int out_size, void* d_ws, size_t ws_size,
                              hipStream_t stream)
{
    const float* x  = (const float*)d_in[0];
    const float* wt = (const float*)d_in[1];
    const float* wp = (const float*)d_in[2];
    const float* wg = (const float*)d_in[3];
    const float* wc = (const float*)d_in[4];
    float* out = (float*)d_out;

    prep_x<<<NXEL_ / 4 / 256, 256, 0, stream>>>(x);
    prep_w<<<(WEL_ + 255) / 256, 256, 0, stream>>>(wt, wp, wg, wc);
    conv3_mfma<<<400, 256, 0, stream>>>();
    prep_pack<<<(NELEM_ + 255) / 256, 256, 0, stream>>>();
    attn_mfma<<<800, 256, 0, stream>>>();
    conv_out_mfma<<<400, 256, 0, stream>>>(x, out);
}

// Round 16
// 680.165 us; speedup vs baseline: 2.6644x; 1.3908x over previous
//
#include <hip/hip_runtime.h>
#include <hip/hip_bf16.h>

#define HH_ 80
#define WW_ 80
#define CIN_ 256
#define NF_ 128
#define NPIX_ 6400
#define NTOK_ 12800
#define NELEM_ (NTOK_ * NF_)       // 1,638,400
#define NXEL_  (NTOK_ * CIN_)      // 3,276,800
#define KW_    2304                // 9*256  (conv3 K)
#define KWC_   1152                // 9*128  (conv_out K)
#define WEL_   294912

// fp32 conv outputs (consumed by prep_pack)
__device__ float g_theta[NELEM_];
__device__ float g_phi  [NELEM_];
__device__ float g_gv   [NELEM_];
// bf16 attention output (consumed by conv_out_mfma)
__device__ unsigned short g_aob[NELEM_];
// bf16 MFMA operands for attention
__device__ unsigned short g_th_hi[NELEM_], g_th_lo[NELEM_];
__device__ unsigned short g_phT_hi[NELEM_], g_phT_lo[NELEM_];
__device__ unsigned short g_gT[NELEM_];
// bf16 hi/lo split of x, and transposed bf16 weights [f][k]
__device__ unsigned short g_xh[NXEL_], g_xl[NXEL_];
__device__ unsigned short g_wtTh[WEL_], g_wtTl[WEL_];
__device__ unsigned short g_wpTh[WEL_], g_wpTl[WEL_];
__device__ unsigned short g_wgT[WEL_];
__device__ unsigned short g_wcT[WEL_];

__device__ __forceinline__ float b2f(unsigned short u) {
    union { unsigned int i; float f; } v; v.i = ((unsigned int)u) << 16; return v.f;
}
__device__ __forceinline__ unsigned short f2b(float f) {
    union { float f; unsigned int i; } v; v.f = f;
    unsigned int i = v.i;
    i += 0x7fffu + ((i >> 16) & 1u);   // RNE (finite only)
    return (unsigned short)(i >> 16);
}

typedef __attribute__((ext_vector_type(8))) short bf16x8;
typedef __attribute__((ext_vector_type(4))) float f32x4;

__device__ __forceinline__ f32x4 mfma16(bf16x8 a, bf16x8 b, f32x4 c) {
    return __builtin_amdgcn_mfma_f32_16x16x32_bf16(a, b, c, 0, 0, 0);
}

// ---------------------------------------------------------------------------
// prep_x: fp32 x -> bf16 hi/lo split
// ---------------------------------------------------------------------------
__global__ __launch_bounds__(256) void prep_x(const float* __restrict__ x)
{
    const int i = (blockIdx.x * 256 + threadIdx.x) * 4;
    if (i >= NXEL_) return;
    const float4 v = *(const float4*)(x + i);
    ushort4 hi, lo;
    hi.x = f2b(v.x); lo.x = f2b(v.x - b2f(hi.x));
    hi.y = f2b(v.y); lo.y = f2b(v.y - b2f(hi.y));
    hi.z = f2b(v.z); lo.z = f2b(v.z - b2f(hi.z));
    hi.w = f2b(v.w); lo.w = f2b(v.w - b2f(hi.w));
    *(ushort4*)(g_xh + i) = hi;
    *(ushort4*)(g_xl + i) = lo;
}

// ---------------------------------------------------------------------------
// prep_w: transpose HWIO weights to [f][k] bf16 (hi/lo for w_theta/w_phi)
// ---------------------------------------------------------------------------
__global__ __launch_bounds__(256) void prep_w(
    const float* __restrict__ wt, const float* __restrict__ wp,
    const float* __restrict__ wg, const float* __restrict__ wc)
{
    const int i = blockIdx.x * 256 + threadIdx.x;
    if (i >= WEL_) return;
    {
        const int t  = i / (256 * 128);
        const int r  = i % (256 * 128);
        const int ci = r >> 7;
        const int f  = r & 127;
        const size_t d = (size_t)f * KW_ + t * 256 + ci;
        const float tv = wt[i];
        const unsigned short th = f2b(tv);
        g_wtTh[d] = th; g_wtTl[d] = f2b(tv - b2f(th));
        const float pv = wp[i];
        const unsigned short ph = f2b(pv);
        g_wpTh[d] = ph; g_wpTl[d] = f2b(pv - b2f(ph));
        g_wgT[d] = f2b(wg[i]);
    }
    {
        const int t  = i / (128 * 256);
        const int r  = i % (128 * 256);
        const int ci = r >> 8;
        const int f  = r & 255;
        g_wcT[(size_t)f * KWC_ + t * 128 + ci] = f2b(wc[i]);
    }
}

// ---------------------------------------------------------------------------
// conv3_mfma: implicit-GEMM 3x3 conv, 3 heads fused (r15, verified).
// ---------------------------------------------------------------------------
__global__ __launch_bounds__(256) void conv3_mfma()
{
    const int tid = threadIdx.x;
    const int w = tid >> 6, lane = tid & 63, quad = lane >> 4, ll = lane & 15;
    const int P0 = blockIdx.x * 32;
    const int fb = w * 32;

    int pb[2], ph[2], pw[2];
    #pragma unroll
    for (int pt = 0; pt < 2; ++pt) {
        const int p = P0 + pt * 16 + ll;
        pb[pt] = p / NPIX_;
        const int pl_ = p % NPIX_;
        ph[pt] = pl_ / WW_;
        pw[pt] = pl_ % WW_;
    }

    const bf16x8 ZV = {0,0,0,0,0,0,0,0};
    f32x4 aT[2][2], aP[2][2], aG[2][2];
    #pragma unroll
    for (int pt = 0; pt < 2; ++pt)
        #pragma unroll
        for (int ft = 0; ft < 2; ++ft) {
            aT[pt][ft] = (f32x4){0.f,0.f,0.f,0.f};
            aP[pt][ft] = (f32x4){0.f,0.f,0.f,0.f};
            aG[pt][ft] = (f32x4){0.f,0.f,0.f,0.f};
        }

    for (int t = 0; t < 9; ++t) {
        const int dh = t / 3 - 1, dw = t % 3 - 1;
        size_t abase[2]; bool av[2];
        #pragma unroll
        for (int pt = 0; pt < 2; ++pt) {
            const int hh = ph[pt] + dh, ww2 = pw[pt] + dw;
            av[pt] = (hh >= 0 && hh < HH_ && ww2 >= 0 && ww2 < WW_);
            abase[pt] = ((size_t)pb[pt] * NPIX_ + hh * WW_ + ww2) * CIN_;
        }
        const int wkb = t * 256;
        for (int kc = 0; kc < 8; ++kc) {
            const int ko = kc * 32 + quad * 8;
            bf16x8 aH[2], aL[2];
            #pragma unroll
            for (int pt = 0; pt < 2; ++pt) {
                if (av[pt]) {
                    aH[pt] = *(const bf16x8*)(g_xh + abase[pt] + ko);
                    aL[pt] = *(const bf16x8*)(g_xl + abase[pt] + ko);
                } else { aH[pt] = ZV; aL[pt] = ZV; }
            }
            const int wk = wkb + ko;
            #pragma unroll
            for (int ft = 0; ft < 2; ++ft) {
                const size_t wo = (size_t)(fb + ft * 16 + ll) * KW_ + wk;
                const bf16x8 tH = *(const bf16x8*)(g_wtTh + wo);
                const bf16x8 tL = *(const bf16x8*)(g_wtTl + wo);
                const bf16x8 pH = *(const bf16x8*)(g_wpTh + wo);
                const bf16x8 pL = *(const bf16x8*)(g_wpTl + wo);
                const bf16x8 gB = *(const bf16x8*)(g_wgT + wo);
                #pragma unroll
                for (int pt = 0; pt < 2; ++pt) {
                    aT[pt][ft] = mfma16(aH[pt], tH, aT[pt][ft]);
                    aT[pt][ft] = mfma16(aH[pt], tL, aT[pt][ft]);
                    aT[pt][ft] = mfma16(aL[pt], tH, aT[pt][ft]);
                    aP[pt][ft] = mfma16(aH[pt], pH, aP[pt][ft]);
                    aP[pt][ft] = mfma16(aH[pt], pL, aP[pt][ft]);
                    aP[pt][ft] = mfma16(aL[pt], pH, aP[pt][ft]);
                    aG[pt][ft] = mfma16(aH[pt], gB, aG[pt][ft]);
                }
            }
        }
    }

    #pragma unroll
    for (int pt = 0; pt < 2; ++pt)
        #pragma unroll
        for (int ft = 0; ft < 2; ++ft) {
            const int f = fb + ft * 16 + ll;
            #pragma unroll
            for (int r = 0; r < 4; ++r) {
                const size_t n = P0 + pt * 16 + quad * 4 + r;
                g_theta[n * NF_ + f] = aT[pt][ft][r];
                g_phi  [n * NF_ + f] = aP[pt][ft][r];
                g_gv   [n * NF_ + f] = aG[pt][ft][r];
            }
        }
}

// ---------------------------------------------------------------------------
// prep_pack (r14, verified)
// ---------------------------------------------------------------------------
__global__ __launch_bounds__(256) void prep_pack()
{
    const int i = blockIdx.x * 256 + threadIdx.x;
    if (i >= NELEM_) return;
    const int n  = i >> 7;
    const int c  = i & 127;
    const int b  = n / NPIX_;
    const int nl = n % NPIX_;

    const float tv = g_theta[i];
    const unsigned short th = f2b(tv);
    g_th_hi[i] = th;
    g_th_lo[i] = f2b(tv - b2f(th));

    const float pv = g_phi[i];
    const int j  = nl * 128 + c;
    const int cp = j / NPIX_;
    const int mp = j % NPIX_;
    const unsigned short phh = f2b(pv);
    const size_t o = (size_t)b * (NPIX_ * NF_) + (size_t)mp * 128 + cp;
    g_phT_hi[o] = phh;
    g_phT_lo[o] = f2b(pv - b2f(phh));

    g_gT[(size_t)b * (NPIX_ * NF_) + (size_t)c * NPIX_ + nl] = f2b(g_gv[i]);
}

// ---------------------------------------------------------------------------
// attn_mfma v2: 32 Q-rows/block, 4 waves, each wave owns ALL 32 rows and a
// 4-way split of m (64-m chunks, stride 256). Halves phi/g L2 traffic per
// Q-row and doubles per-iter MFMA:load ratio vs r14/r15 (16 rows/wave).
// Split-KV merge via bf16 O-partials in LDS. Per-wave P-LDS: no barrier in
// the K-loop. VGPR ~220 -> __launch_bounds__(256,2); grid 400 (all resident).
// ---------------------------------------------------------------------------
__global__ __launch_bounds__(256, 2) void attn_mfma()
{
    __shared__ __align__(16) short p_lds[4][32 * 72];       // 18.4 KB
    __shared__ unsigned short o_lds[4][32][136];            // 34.8 KB (bf16)
    __shared__ float ml_lds[4][32][2];                      // 1 KB

    const int tid  = threadIdx.x;
    const int w    = tid >> 6;
    const int lane = tid & 63;
    const int quad = lane >> 4;
    const int ll   = lane & 15;
    const int R0   = blockIdx.x * 32;     // 32 | 6400 -> no batch straddle
    const int b    = R0 / NPIX_;

    const unsigned short* phH = g_phT_hi + (size_t)b * (NPIX_ * NF_);
    const unsigned short* phL = g_phT_lo + (size_t)b * (NPIX_ * NF_);
    const unsigned short* gT  = g_gT    + (size_t)b * (NPIX_ * NF_);

    // theta A-fragments: 2 row-tiles x 4 k-steps x {hi,lo}
    bf16x8 aH[2][4], aL[2][4];
    #pragma unroll
    for (int rt = 0; rt < 2; ++rt)
        #pragma unroll
        for (int kk = 0; kk < 4; ++kk) {
            const size_t off = (size_t)(R0 + rt * 16 + ll) * 128 + kk * 32 + quad * 8;
            aH[rt][kk] = *(const bf16x8*)(g_th_hi + off);
            aL[rt][kk] = *(const bf16x8*)(g_th_lo + off);
        }

    f32x4 acc[2][8];
    #pragma unroll
    for (int rt = 0; rt < 2; ++rt)
        #pragma unroll
        for (int t = 0; t < 8; ++t) acc[rt][t] = (f32x4){0.f, 0.f, 0.f, 0.f};
    float mi[2][4], li[2][4];
    #pragma unroll
    for (int rt = 0; rt < 2; ++rt)
        #pragma unroll
        for (int r = 0; r < 4; ++r) { mi[rt][r] = -1e30f; li[rt][r] = 0.f; }

    short* pl = &p_lds[w][0];

    for (int it = 0; it < 25; ++it) {
        const int m0 = it * 256 + w * 64;   // this wave's 64-m chunk

        // ---- S phase: 4 m-tiles x 4 k-steps, hi/lo split, 2 row-tiles ------
        f32x4 s[2][4];
        #pragma unroll
        for (int mt = 0; mt < 4; ++mt) {
            f32x4 s0 = (f32x4){0.f,0.f,0.f,0.f};
            f32x4 s1 = (f32x4){0.f,0.f,0.f,0.f};
            const int mm = m0 + mt * 16 + ll;
            #pragma unroll
            for (int kk = 0; kk < 4; ++kk) {
                const size_t off = (size_t)mm * 128 + kk * 32 + quad * 8;
                const bf16x8 bH = *(const bf16x8*)(phH + off);
                const bf16x8 bL = *(const bf16x8*)(phL + off);
                s0 = mfma16(aH[0][kk], bH, s0);
                s0 = mfma16(aH[0][kk], bL, s0);
                s0 = mfma16(aL[0][kk], bH, s0);
                s1 = mfma16(aH[1][kk], bH, s1);
                s1 = mfma16(aH[1][kk], bL, s1);
                s1 = mfma16(aL[1][kk], bH, s1);
            }
            s[0][mt] = s0; s[1][mt] = s1;
        }

        // ---- online softmax per row-tile, per row --------------------------
        #pragma unroll
        for (int rt = 0; rt < 2; ++rt)
            #pragma unroll
            for (int r = 0; r < 4; ++r) {
                float cm = fmaxf(fmaxf(s[rt][0][r], s[rt][1][r]),
                                 fmaxf(s[rt][2][r], s[rt][3][r]));
                cm = fmaxf(cm, __shfl_xor(cm, 1));
                cm = fmaxf(cm, __shfl_xor(cm, 2));
                cm = fmaxf(cm, __shfl_xor(cm, 4));
                cm = fmaxf(cm, __shfl_xor(cm, 8));
                const float nm = fmaxf(mi[rt][r], cm);
                const float al = __expf(mi[rt][r] - nm);
                mi[rt][r] = nm;
                float ssum = 0.f;
                #pragma unroll
                for (int mt = 0; mt < 4; ++mt) {
                    const float e = __expf(s[rt][mt][r] - nm);
                    s[rt][mt][r] = e; ssum += e;
                }
                ssum += __shfl_xor(ssum, 1);
                ssum += __shfl_xor(ssum, 2);
                ssum += __shfl_xor(ssum, 4);
                ssum += __shfl_xor(ssum, 8);
                li[rt][r] = li[rt][r] * al + ssum;
                #pragma unroll
                for (int t = 0; t < 8; ++t) acc[rt][t][r] *= al;
            }

        // ---- P (C-layout) -> per-wave LDS [row][m] bf16 -> A-fragments -----
        #pragma unroll
        for (int rt = 0; rt < 2; ++rt)
            #pragma unroll
            for (int mt = 0; mt < 4; ++mt)
                #pragma unroll
                for (int r = 0; r < 4; ++r)
                    pl[(rt * 16 + quad * 4 + r) * 72 + mt * 16 + ll] =
                        (short)f2b(s[rt][mt][r]);
        bf16x8 pa[2][2];
        #pragma unroll
        for (int rt = 0; rt < 2; ++rt)
            #pragma unroll
            for (int ks = 0; ks < 2; ++ks)
                pa[rt][ks] = *(const bf16x8*)(
                    pl + (rt * 16 + ll) * 72 + ks * 32 + quad * 8);

        // ---- PV: 8 channel-tiles x 2 k-steps; g-load shared by row-tiles ---
        #pragma unroll
        for (int ct = 0; ct < 8; ++ct) {
            #pragma unroll
            for (int ks = 0; ks < 2; ++ks) {
                const bf16x8 gb = *(const bf16x8*)(
                    gT + (size_t)(ct * 16 + ll) * NPIX_ + m0 + ks * 32 + quad * 8);
                acc[0][ct] = mfma16(pa[0][ks], gb, acc[0][ct]);
                acc[1][ct] = mfma16(pa[1][ks], gb, acc[1][ct]);
            }
        }
    }

    // ---- split-KV merge across the 4 waves (bf16 partials) -----------------
    #pragma unroll
    for (int rt = 0; rt < 2; ++rt)
        #pragma unroll
        for (int ct = 0; ct < 8; ++ct)
            #pragma unroll
            for (int r = 0; r < 4; ++r)
                o_lds[w][rt * 16 + quad * 4 + r][ct * 16 + ll] =
                    f2b(acc[rt][ct][r]);
    if (ll == 0) {
        #pragma unroll
        for (int rt = 0; rt < 2; ++rt)
            #pragma unroll
            for (int r = 0; r < 4; ++r) {
                ml_lds[w][rt * 16 + quad * 4 + r][0] = mi[rt][r];
                ml_lds[w][rt * 16 + quad * 4 + r][1] = li[rt][r];
            }
    }
    __syncthreads();

    const int n  = tid >> 3;           // 0..31
    const int c0 = (tid & 7) * 16;
    const float M = fmaxf(fmaxf(ml_lds[0][n][0], ml_lds[1][n][0]),
                          fmaxf(ml_lds[2][n][0], ml_lds[3][n][0]));
    float sc[4], L = 0.f;
    #pragma unroll
    for (int ww = 0; ww < 4; ++ww) {
        sc[ww] = __expf(ml_lds[ww][n][0] - M);
        L += ml_lds[ww][n][1] * sc[ww];
    }
    const float inv = 1.f / L;
    unsigned short tmp[16];
    #pragma unroll
    for (int j = 0; j < 16; ++j) {
        float o = 0.f;
        #pragma unroll
        for (int ww = 0; ww < 4; ++ww)
            o += b2f(o_lds[ww][n][c0 + j]) * sc[ww];
        tmp[j] = f2b(o * inv);
    }
    #pragma unroll
    for (int j = 0; j < 16; j += 4)
        *(ushort4*)(g_aob + (size_t)(R0 + n) * 128 + c0 + j) =
            make_ushort4(tmp[j], tmp[j+1], tmp[j+2], tmp[j+3]);
}

// ---------------------------------------------------------------------------
// conv_out_mfma: implicit-GEMM 3x3 conv (128->256, bf16) + fp32 residual
// ---------------------------------------------------------------------------
__global__ __launch_bounds__(256) void conv_out_mfma(
    const float* __restrict__ x, float* __restrict__ out)
{
    const int tid = threadIdx.x;
    const int w = tid >> 6, lane = tid & 63, quad = lane >> 4, ll = lane & 15;
    const int P0 = blockIdx.x * 32;
    const int fb = w * 64;

    int pb[2], ph[2], pw[2];
    #pragma unroll
    for (int pt = 0; pt < 2; ++pt) {
        const int p = P0 + pt * 16 + ll;
        pb[pt] = p / NPIX_;
        const int pl_ = p % NPIX_;
        ph[pt] = pl_ / WW_;
        pw[pt] = pl_ % WW_;
    }

    const bf16x8 ZV = {0,0,0,0,0,0,0,0};
    f32x4 acc[2][4];
    #pragma unroll
    for (int pt = 0; pt < 2; ++pt)
        #pragma unroll
        for (int ft = 0; ft < 4; ++ft) acc[pt][ft] = (f32x4){0.f,0.f,0.f,0.f};

    for (int t = 0; t < 9; ++t) {
        const int dh = t / 3 - 1, dw = t % 3 - 1;
        size_t abase[2]; bool av[2];
        #pragma unroll
        for (int pt = 0; pt < 2; ++pt) {
            const int hh = ph[pt] + dh, ww2 = pw[pt] + dw;
            av[pt] = (hh >= 0 && hh < HH_ && ww2 >= 0 && ww2 < WW_);
            abase[pt] = ((size_t)pb[pt] * NPIX_ + hh * WW_ + ww2) * NF_;
        }
        for (int kc = 0; kc < 4; ++kc) {
            const int ko = kc * 32 + quad * 8;
            bf16x8 a[2];
            #pragma unroll
            for (int pt = 0; pt < 2; ++pt)
                a[pt] = av[pt] ? *(const bf16x8*)(g_aob + abase[pt] + ko) : ZV;
            const int wk = t * 128 + ko;
            #pragma unroll
            for (int ft = 0; ft < 4; ++ft) {
                const bf16x8 bw = *(const bf16x8*)(
                    g_wcT + (size_t)(fb + ft * 16 + ll) * KWC_ + wk);
                #pragma unroll
                for (int pt = 0; pt < 2; ++pt)
                    acc[pt][ft] = mfma16(a[pt], bw, acc[pt][ft]);
            }
        }
    }

    #pragma unroll
    for (int pt = 0; pt < 2; ++pt)
        #pragma unroll
        for (int ft = 0; ft < 4; ++ft) {
            const int f = fb + ft * 16 + ll;
            #pragma unroll
            for (int r = 0; r < 4; ++r) {
                const size_t n = P0 + pt * 16 + quad * 4 + r;
                const size_t oi = n * CIN_ + f;
                out[oi] = x[oi] + acc[pt][ft][r];
            }
        }
}

// ---------------------------------------------------------------------------
extern "C" void kernel_launch(void* const* d_in, const int* in_sizes, int n_in,
                              void* d_out, int out_size, void* d_ws, size_t ws_size,
                              hipStream_t stream)
{
    const float* x  = (const float*)d_in[0];
    const float* wt = (const float*)d_in[1];
    const float* wp = (const float*)d_in[2];
    const float* wg = (const float*)d_in[3];
    const float* wc = (const float*)d_in[4];
    float* out = (float*)d_out;

    prep_x<<<NXEL_ / 4 / 256, 256, 0, stream>>>(x);
    prep_w<<<(WEL_ + 255) / 256, 256, 0, stream>>>(wt, wp, wg, wc);
    conv3_mfma<<<400, 256, 0, stream>>>();
    prep_pack<<<(NELEM_ + 255) / 256, 256, 0, stream>>>();
    attn_mfma<<<400, 256, 0, stream>>>();
    conv_out_mfma<<<400, 256, 0, stream>>>(x, out);
}